// Round 1
// baseline (133.740 us; speedup 1.0000x reference)
//
#include <hip/hip_runtime.h>

// Problem constants (from reference): src (B,C,D,H,W) f32, flow (B,3,D,H,W) f32
constexpr int B  = 2;
constexpr int C  = 1;
constexpr int D  = 160;
constexpr int H  = 192;
constexpr int W  = 224;
constexpr int HW = H * W;            // 43008
constexpr int N  = D * HW;           // 6,881,280 voxels per (b,c) volume
constexpr int TOTAL = B * C * N;     // 13,762,560 output elements

__global__ __launch_bounds__(256) void st3d_warp_kernel(
    const float* __restrict__ src,
    const float* __restrict__ flow,
    float* __restrict__ out)
{
    int gid = blockIdx.x * blockDim.x + threadIdx.x;
    if (gid >= TOTAL) return;

    // decompose gid -> (b, z, y, x)   (C == 1)
    int b = gid / N;
    int n = gid - b * N;
    int z = n / HW;
    int r = n - z * HW;
    int y = r / W;
    int x = r - y * W;

    const float* fl = flow + (size_t)b * 3 * N;
    float cz = (float)z + fl[n];
    float cy = (float)y + fl[N + n];
    float cx = (float)x + fl[2 * N + n];

    float fz0 = floorf(cz); int z0 = (int)fz0; float fz = cz - fz0;
    float fy0 = floorf(cy); int y0 = (int)fy0; float fy = cy - fy0;
    float fx0 = floorf(cx); int x0 = (int)fx0; float fx = cx - fx0;
    int z1 = z0 + 1, y1 = y0 + 1, x1 = x0 + 1;

    // per-axis weights with validity mask folded in (corner valid = vz&vy&vx
    // factors into the product, identical to reference semantics)
    float wz0 = (1.0f - fz) * ((z0 >= 0 && z0 < D) ? 1.0f : 0.0f);
    float wz1 = fz          * ((z1 >= 0 && z1 < D) ? 1.0f : 0.0f);
    float wy0 = (1.0f - fy) * ((y0 >= 0 && y0 < H) ? 1.0f : 0.0f);
    float wy1 = fy          * ((y1 >= 0 && y1 < H) ? 1.0f : 0.0f);
    float wx0 = (1.0f - fx) * ((x0 >= 0 && x0 < W) ? 1.0f : 0.0f);
    float wx1 = fx          * ((x1 >= 0 && x1 < W) ? 1.0f : 0.0f);

    // clamped indices (clip like reference; weight 0 kills OOB contributions)
    int zc0 = min(max(z0, 0), D - 1), zc1 = min(max(z1, 0), D - 1);
    int yc0 = min(max(y0, 0), H - 1), yc1 = min(max(y1, 0), H - 1);
    int xc0 = min(max(x0, 0), W - 1), xc1 = min(max(x1, 0), W - 1);

    const float* s  = src + (size_t)b * N;   // C == 1
    const float* sz0 = s + zc0 * HW;
    const float* sz1 = s + zc1 * HW;
    int ry0 = yc0 * W, ry1 = yc1 * W;

    float v000 = sz0[ry0 + xc0], v001 = sz0[ry0 + xc1];
    float v010 = sz0[ry1 + xc0], v011 = sz0[ry1 + xc1];
    float v100 = sz1[ry0 + xc0], v101 = sz1[ry0 + xc1];
    float v110 = sz1[ry1 + xc0], v111 = sz1[ry1 + xc1];

    float acc = v000 * (wz0 * wy0 * wx0) + v001 * (wz0 * wy0 * wx1)
              + v010 * (wz0 * wy1 * wx0) + v011 * (wz0 * wy1 * wx1)
              + v100 * (wz1 * wy0 * wx0) + v101 * (wz1 * wy0 * wx1)
              + v110 * (wz1 * wy1 * wx0) + v111 * (wz1 * wy1 * wx1);

    out[gid] = acc;
}

extern "C" void kernel_launch(void* const* d_in, const int* in_sizes, int n_in,
                              void* d_out, int out_size, void* d_ws, size_t ws_size,
                              hipStream_t stream)
{
    const float* src  = (const float*)d_in[0];
    const float* flow = (const float*)d_in[1];
    float* out = (float*)d_out;

    int blocks = (TOTAL + 255) / 256;
    st3d_warp_kernel<<<blocks, 256, 0, stream>>>(src, flow, out);
}